// Round 4
// baseline (170.969 us; speedup 1.0000x reference)
//
#include <hip/hip_runtime.h>
#include <hip/hip_bf16.h>

// Problem constants
#define B_ 4
#define N_ 4096
#define D_ 1024
#define H_ 16
#define INNER_ 1024
#define M_ (B_ * N_)   // 16384 rows
#define CH_ 128        // scan chunks
#define CL_ 32         // chunk length = N_/CH_

using bf16x8 = __attribute__((ext_vector_type(8))) __bf16;
using f32x4  = __attribute__((ext_vector_type(4))) float;

__device__ __forceinline__ float bf2f(unsigned short v) {
  return __uint_as_float(((unsigned)v) << 16);
}
__device__ __forceinline__ unsigned short f2bf(float f) {
  __hip_bfloat16 h = __float2bfloat16(f);
  return *reinterpret_cast<unsigned short*>(&h);
}
__device__ __forceinline__ float sigm(float x) { return 1.f / (1.f + expf(-x)); }

__device__ __forceinline__ void gload_lds16(const void* g, void* l) {
  __builtin_amdgcn_global_load_lds(
      (const __attribute__((address_space(1))) unsigned int*)g,
      (__attribute__((address_space(3))) unsigned int*)l, 16, 0, 0);
}

// ---------------- weight casts f32 -> bf16 (both weights, one launch) ----------------
#define W4_ ((INNER_ * D_) / 4)
__global__ __launch_bounds__(256) void cast2_kernel(
    const float* __restrict__ wa, const float* __restrict__ wb,
    __hip_bfloat16* __restrict__ oa, __hip_bfloat16* __restrict__ ob) {
  int i = blockIdx.x * 256 + threadIdx.x;
  const float* src = (i < W4_) ? wa : wb;
  __hip_bfloat16* dst = (i < W4_) ? oa : ob;
  int j = (i < W4_) ? i : i - W4_;
  float4 v = reinterpret_cast<const float4*>(src)[j];
  ushort4 o;
  o.x = f2bf(v.x); o.y = f2bf(v.y); o.z = f2bf(v.z); o.w = f2bf(v.w);
  reinterpret_cast<ushort4*>(dst)[j] = o;
}

// ---------------- LayerNorm (one block per row) ----------------
__global__ __launch_bounds__(256) void ln_kernel(
    const float* __restrict__ x, const float* __restrict__ gamma,
    const float* __restrict__ beta, __hip_bfloat16* __restrict__ xn) {
  const long row = blockIdx.x;
  const int t = threadIdx.x;
  const float4 v = reinterpret_cast<const float4*>(x + row * D_)[t];
  float s = v.x + v.y + v.z + v.w;
  float s2 = v.x * v.x + v.y * v.y + v.z * v.z + v.w * v.w;
#pragma unroll
  for (int o = 32; o > 0; o >>= 1) {
    s += __shfl_down(s, o);
    s2 += __shfl_down(s2, o);
  }
  __shared__ float red[8];
  const int lane = t & 63, wv = t >> 6;
  if (lane == 0) { red[wv] = s; red[4 + wv] = s2; }
  __syncthreads();
  const float sum = red[0] + red[1] + red[2] + red[3];
  const float sum2 = red[4] + red[5] + red[6] + red[7];
  const float mu = sum * (1.f / D_);
  const float var = sum2 * (1.f / D_) - mu * mu;
  const float rs = rsqrtf(var + 1e-5f);
  const float4 g = reinterpret_cast<const float4*>(gamma)[t];
  const float4 bb = reinterpret_cast<const float4*>(beta)[t];
  ushort4 o;
  o.x = f2bf((v.x - mu) * rs * g.x + bb.x);
  o.y = f2bf((v.y - mu) * rs * g.y + bb.y);
  o.z = f2bf((v.z - mu) * rs * g.z + bb.z);
  o.w = f2bf((v.w - mu) * rs * g.w + bb.w);
  reinterpret_cast<ushort4*>(xn + row * D_)[t] = o;
}

// ---------------- 256x256 bf16 NT GEMM: A via LDS ring-4, B direct-to-VGPR ----------------
// C[m,n] = sum_k A[m,k] * Bt[n,k].  8 waves (2M x 4N), per-wave C = 128x64.
// A: LDS ring 4 slots x 16KB (swizzled, 0 conflicts verified r2/r3), staged t+2 ahead.
// B: per-tile fragments loaded global->VGPR (16 rows x 64B contiguous per wave, L1/L2
//    resident: all blocks on an XCD share one 512KB B-slice), 1-tile prefetch (bv0/bv1).
// vmcnt(6) boundary wait: 6 newest vmem ops = stage(t+2)[2] + bv(t+1)[4] in flight,
// guarantees stage(t+1) and bv(t) landed. Single barrier per tile (r2 structure).
__device__ __forceinline__ void stc(float* p, float v) { *p = v; }
__device__ __forceinline__ void stc(__hip_bfloat16* p, float v) { *p = __float2bfloat16(v); }

template <typename TOUT, int NT>
__global__ __launch_bounds__(512, 1) void gemm256_kernel(
    const __hip_bfloat16* __restrict__ A, const __hip_bfloat16* __restrict__ Bt,
    TOUT* __restrict__ C, int M, int N, int K) {
  static_assert(NT >= 4 && (NT % 4) == 0, "ring needs multiple-of-4 tiles");
  __shared__ __align__(16) char lds[65536];
  const int tid = threadIdx.x;
  const int lane = tid & 63;
  const int wave = tid >> 6;

  // XCD-aware bijective swizzle (grid is 4 x 64 = 256 blocks = 8 XCDs x 32)
  int wg = blockIdx.y * gridDim.x + blockIdx.x;
  wg = (wg & 7) * 32 + (wg >> 3);
  const int bx = wg & 3;   // gridDim.x == 4
  const int by = wg >> 2;
  const long bm = (long)by * 256;
  const long bn = (long)bx * 256;

  // ---- A staging source (pre-swizzled global address, per-thread constant) ----
  const int u0  = (tid & 7) ^ ((tid >> 3) & 7);
  const int r0  = 2 * (tid >> 3) + (u0 >> 2);   // logical row
  const int ck0 = u0 & 3;                        // logical 16B k-chunk
  const __hip_bfloat16* sA0 = A + (bm + r0) * (long)K + ck0 * 8;
  const __hip_bfloat16* sA1 = sA0 + 128l * K;
  char* dbase = (char*)lds + wave * 1024;        // wave-uniform LDS dest base

  // ---- reader constants ----
  const int wm = wave >> 2;   // 0..1
  const int wn = wave & 3;    // 0..3
  const int fr = lane & 15;
  const int ck = lane >> 4;   // 0..3 (k-chunk of the MFMA fragment)
  const int pos = (((fr & 1) << 2) | ck) ^ ((fr >> 1) & 7);
  const int laneA = wm * 8192 + (fr >> 1) * 128 + pos * 16;
  // B fragment source: lane reads Bt[bn + wn*64 + cf*16 + fr][kt*32 + ck*8 .. +8]
  const __hip_bfloat16* gBv = Bt + (bn + wn * 64 + fr) * (long)K + ck * 8;

  f32x4 acc[8][4] = {};

#define STAGE_A(kt) do { const int _s = (kt) & 3;                         \
    gload_lds16(sA0 + (long)(kt) * 32, dbase + _s * 16384);               \
    gload_lds16(sA1 + (long)(kt) * 32, dbase + _s * 16384 + 8192); } while (0)
#define BVL(dst, kt) do {                                                  \
    dst[0] = *(const bf16x8*)(gBv + (long)(kt) * 32);                      \
    dst[1] = *(const bf16x8*)(gBv + (long)(kt) * 32 + 16l * K);            \
    dst[2] = *(const bf16x8*)(gBv + (long)(kt) * 32 + 32l * K);            \
    dst[3] = *(const bf16x8*)(gBv + (long)(kt) * 32 + 48l * K); } while (0)
#define AVL(av, tt) do { const char* _b = (const char*)lds + ((tt) & 3) * 16384; \
    _Pragma("unroll")                                                      \
    for (int r = 0; r < 8; ++r) av[r] = *(const bf16x8*)(_b + laneA + r * 1024); } while (0)
#define MFMA32(av, bv, ro) do {                                            \
    __builtin_amdgcn_s_setprio(1);                                         \
    _Pragma("unroll")                                                      \
    for (int r = 0; r < 8; ++r)                                            \
      _Pragma("unroll")                                                    \
      for (int c = 0; c < 4; ++c)                                          \
        acc[r][c] = __builtin_amdgcn_mfma_f32_16x16x32_bf16(av[r], bv[c], acc[r][c], 0, 0, 0); \
    __builtin_amdgcn_s_setprio(0); } while (0)
#define SBAR() asm volatile("s_barrier" ::: "memory")
#define WAIT6() asm volatile("s_waitcnt vmcnt(6)" ::: "memory")

  bf16x8 bv0[4], bv1[4];
  // prologue: stage A tiles 0,1; prefetch bv tile 0; land stage(0)
  STAGE_A(0); STAGE_A(1);
  BVL(bv0, 0);
  WAIT6();      // own stage(0) [oldest 2 of 8] landed; stage(1)+bv0 may fly
  SBAR();       // all waves' stage(0) landed (each waited before arriving)

#pragma unroll 2
  for (int t = 0; t < NT; t += 2) {
    // ---- tile t (even): consume bv0, prefetch bv1 ----
    {
      bf16x8 av[8];
      AVL(av, t);
      if (t + 2 < NT) STAGE_A(t + 2);
      BVL(bv1, t + 1);
      MFMA32(av, bv0, 0);
      WAIT6();  // stage(t+1) landed (bv(t) already forced landed by compiler wait)
      SBAR();
    }
    // ---- tile t+1 (odd): consume bv1, prefetch bv0 ----
    {
      bf16x8 av[8];
      AVL(av, t + 1);
      if (t + 3 < NT) STAGE_A(t + 3);
      if (t + 2 < NT) BVL(bv0, t + 2);
      MFMA32(av, bv1, 0);
      if (t + 2 < NT) { WAIT6(); SBAR(); }  // last boundary: epilogue reads no LDS
    }
  }
#undef STAGE_A
#undef BVL
#undef AVL
#undef MFMA32
#undef SBAR
#undef WAIT6

  // epilogue: C/D layout (m89-verified): col = lane&15, row = (lane>>4)*4 + reg
  const int cr = ck * 4;
#pragma unroll
  for (int rf = 0; rf < 8; ++rf)
#pragma unroll
    for (int cf = 0; cf < 4; ++cf)
#pragma unroll
      for (int r = 0; r < 4; ++r) {
        const long row = bm + wm * 128 + rf * 16 + cr + r;
        const long col = bn + wn * 64 + cf * 16 + fr;
        stc(&C[row * (long)N + col], acc[rf][cf][r]);
      }
}

// ---------------- scan phase 1: chunk-local finals only ----------------
__global__ __launch_bounds__(256) void scan_finals_kernel(
    const __hip_bfloat16* __restrict__ xi, float* __restrict__ finals,
    const float* __restrict__ alpha) {
  const int e0 = threadIdx.x * 4;
  const int c = blockIdx.y;
  const int b = blockIdx.z;
  const float a = sigm(alpha[e0 >> 6]);
  const float om = 1.f - a;
  long base = ((long)b * N_ + (long)c * CL_) * INNER_ + e0;
  float y0 = 0.f, y1 = 0.f, y2 = 0.f, y3 = 0.f;
  for (int t = 0; t < CL_; ++t) {
    ushort4 u = *(const ushort4*)(xi + base);
    y0 = om * y0 + a * bf2f(u.x);
    y1 = om * y1 + a * bf2f(u.y);
    y2 = om * y2 + a * bf2f(u.z);
    y3 = om * y3 + a * bf2f(u.w);
    base += INNER_;
  }
  float4 f4 = make_float4(y0, y1, y2, y3);
  *reinterpret_cast<float4*>(&finals[((long)b * CH_ + c) * INNER_ + e0]) = f4;
}

// ---------------- scan phase 2: carry sweep over chunks ----------------
__global__ __launch_bounds__(256) void scan_carry_kernel(
    const float* __restrict__ finals, float* __restrict__ carries,
    const float* __restrict__ alpha) {
  const int g = blockIdx.x * 256 + threadIdx.x;  // 0..B_*INNER_-1
  const int b = g >> 10;
  const int e = g & 1023;
  const float a = sigm(alpha[e >> 6]);
  const float dc = powf(1.f - a, (float)CL_);
  float carry = 0.f;
  for (int c = 0; c < CH_; ++c) {
    const long idx = ((long)b * CH_ + c) * INNER_ + e;
    carries[idx] = carry;
    carry = finals[idx] + dc * carry;
  }
}

// ---------------- scan phase 3: full EMA seeded by carry ----------------
__global__ __launch_bounds__(256) void scan_apply_kernel(
    const __hip_bfloat16* __restrict__ xi, __hip_bfloat16* __restrict__ y,
    const float* __restrict__ carries, const float* __restrict__ alpha) {
  const int e0 = threadIdx.x * 4;
  const int c = blockIdx.y;
  const int b = blockIdx.z;
  const float a = sigm(alpha[e0 >> 6]);
  const float om = 1.f - a;
  const float4 cr = *reinterpret_cast<const float4*>(
      &carries[((long)b * CH_ + c) * INNER_ + e0]);
  float y0 = cr.x, y1 = cr.y, y2 = cr.z, y3 = cr.w;
  long base = ((long)b * N_ + (long)c * CL_) * INNER_ + e0;
  for (int t = 0; t < CL_; ++t) {
    ushort4 u = *(const ushort4*)(xi + base);
    y0 = om * y0 + a * bf2f(u.x);
    y1 = om * y1 + a * bf2f(u.y);
    y2 = om * y2 + a * bf2f(u.z);
    y3 = om * y3 + a * bf2f(u.w);
    ushort4 o;
    o.x = f2bf(y0); o.y = f2bf(y1); o.z = f2bf(y2); o.w = f2bf(y3);
    *(ushort4*)(y + base) = o;
    base += INNER_;
  }
}

extern "C" void kernel_launch(void* const* d_in, const int* in_sizes, int n_in,
                              void* d_out, int out_size, void* d_ws, size_t ws_size,
                              hipStream_t stream) {
  const float* x     = (const float*)d_in[0];
  const float* gamma = (const float*)d_in[1];
  const float* beta  = (const float*)d_in[2];
  const float* alpha = (const float*)d_in[3];
  const float* w_in  = (const float*)d_in[4];
  const float* w_out = (const float*)d_in[5];
  float* out = (float*)d_out;
  char* ws = (char*)d_ws;

  // ws layout (40 MB total):
  __hip_bfloat16* xn = (__hip_bfloat16*)ws;                       // 32 MB (reused as y)
  __hip_bfloat16* wi = (__hip_bfloat16*)(ws + (32l << 20));       // 2 MB
  __hip_bfloat16* wo = (__hip_bfloat16*)(ws + (34l << 20));       // 2 MB
  float* finals      = (float*)(ws + (36l << 20));                // 2 MB
  float* carries     = (float*)(ws + (38l << 20));                // 2 MB
  // xi (bf16, 32 MB) lives in d_out's first half; consumed before GEMM2 writes d_out
  __hip_bfloat16* xi = (__hip_bfloat16*)d_out;

  cast2_kernel<<<2048, 256, 0, stream>>>(w_in, w_out, wi, wo);

  ln_kernel<<<M_, 256, 0, stream>>>(x, gamma, beta, xn);

  // xi[m,e] = sum_d xn[m,d] * w_in[e,d]   (grid 4 x 64 = 256 blocks)
  gemm256_kernel<__hip_bfloat16, 32>
      <<<dim3(INNER_ / 256, M_ / 256), 512, 0, stream>>>(xn, wi, xi, M_, INNER_, D_);

  __hip_bfloat16* y = xn;  // overwrite xn (consumed by GEMM1)
  scan_finals_kernel<<<dim3(1, CH_, B_), 256, 0, stream>>>(xi, finals, alpha);
  scan_carry_kernel<<<(B_ * INNER_) / 256, 256, 0, stream>>>(finals, carries, alpha);
  scan_apply_kernel<<<dim3(1, CH_, B_), 256, 0, stream>>>(xi, y, carries, alpha);

  // out[m,d] = sum_e y[m,e] * w_out[d,e]
  gemm256_kernel<float, 32>
      <<<dim3(D_ / 256, M_ / 256), 512, 0, stream>>>(y, wo, out, M_, D_, INNER_);
}

// Round 5
// 130.145 us; speedup vs baseline: 1.3137x; 1.3137x over previous
//
#include <hip/hip_runtime.h>
#include <hip/hip_bf16.h>

// Problem constants
#define B_ 4
#define N_ 4096
#define D_ 1024
#define H_ 16
#define INNER_ 1024
#define M_ (B_ * N_)   // 16384 rows
#define CH_ 128        // scan chunks
#define CL_ 32         // chunk length = N_/CH_

using bf16x8 = __attribute__((ext_vector_type(8))) __bf16;
using f32x4  = __attribute__((ext_vector_type(4))) float;

__device__ __forceinline__ float bf2f(unsigned short v) {
  return __uint_as_float(((unsigned)v) << 16);
}
__device__ __forceinline__ unsigned short f2bf(float f) {
  __hip_bfloat16 h = __float2bfloat16(f);
  return *reinterpret_cast<unsigned short*>(&h);
}
__device__ __forceinline__ float sigm(float x) { return 1.f / (1.f + expf(-x)); }

__device__ __forceinline__ void gload_lds16(const void* g, void* l) {
  __builtin_amdgcn_global_load_lds(
      (const __attribute__((address_space(1))) unsigned int*)g,
      (__attribute__((address_space(3))) unsigned int*)l, 16, 0, 0);
}

// ---------------- weight casts f32 -> bf16 (both weights, one launch) ----------------
#define W4_ ((INNER_ * D_) / 4)
__global__ __launch_bounds__(256) void cast2_kernel(
    const float* __restrict__ wa, const float* __restrict__ wb,
    __hip_bfloat16* __restrict__ oa, __hip_bfloat16* __restrict__ ob) {
  int i = blockIdx.x * 256 + threadIdx.x;
  const float* src = (i < W4_) ? wa : wb;
  __hip_bfloat16* dst = (i < W4_) ? oa : ob;
  int j = (i < W4_) ? i : i - W4_;
  float4 v = reinterpret_cast<const float4*>(src)[j];
  ushort4 o;
  o.x = f2bf(v.x); o.y = f2bf(v.y); o.z = f2bf(v.z); o.w = f2bf(v.w);
  reinterpret_cast<ushort4*>(dst)[j] = o;
}

// ---------------- LayerNorm (one block per row) ----------------
__global__ __launch_bounds__(256) void ln_kernel(
    const float* __restrict__ x, const float* __restrict__ gamma,
    const float* __restrict__ beta, __hip_bfloat16* __restrict__ xn) {
  const long row = blockIdx.x;
  const int t = threadIdx.x;
  const float4 v = reinterpret_cast<const float4*>(x + row * D_)[t];
  float s = v.x + v.y + v.z + v.w;
  float s2 = v.x * v.x + v.y * v.y + v.z * v.z + v.w * v.w;
#pragma unroll
  for (int o = 32; o > 0; o >>= 1) {
    s += __shfl_down(s, o);
    s2 += __shfl_down(s2, o);
  }
  __shared__ float red[8];
  const int lane = t & 63, wv = t >> 6;
  if (lane == 0) { red[wv] = s; red[4 + wv] = s2; }
  __syncthreads();
  const float sum = red[0] + red[1] + red[2] + red[3];
  const float sum2 = red[4] + red[5] + red[6] + red[7];
  const float mu = sum * (1.f / D_);
  const float var = sum2 * (1.f / D_) - mu * mu;
  const float rs = rsqrtf(var + 1e-5f);
  const float4 g = reinterpret_cast<const float4*>(gamma)[t];
  const float4 bb = reinterpret_cast<const float4*>(beta)[t];
  ushort4 o;
  o.x = f2bf((v.x - mu) * rs * g.x + bb.x);
  o.y = f2bf((v.y - mu) * rs * g.y + bb.y);
  o.z = f2bf((v.z - mu) * rs * g.z + bb.z);
  o.w = f2bf((v.w - mu) * rs * g.w + bb.w);
  reinterpret_cast<ushort4*>(xn + row * D_)[t] = o;
}

// ---------------- 256x256 bf16 NT GEMM, faithful 8-phase half-tile-ring port ----------------
// C[m,n] = sum_k A[m,k]*Bt[n,k]. 8 waves (2M x 4N). Per-wave output 128x64 STRIDED across
// block halves: rows {wm*64..+63} U {128+wm*64..+63}, cols {wn*32..+31} U {128+wn*32..+31}.
// => in any quadrant phase ALL waves read the SAME block A-half / B-half, so halves free
// early and can be restaged mid-tile (the m201 half-tile pipeline precondition).
// LDS: A-ring 4 half-slots x 16KB + B-ring same = 128KB. Half h = K-tile (h>>1), row-half (h&1).
// Tile t phases: ph1 Q(0,0) rd A(2t)+B(2t), stage A,B(2t+3); ph2 Q(0,1) rd B(2t+1);
// ph3 Q(1,0) rd A(2t+1), stage A(2t+4); ph4 Q(1,1) rd none, stage B(2t+4), vmcnt(4).
// Every stage lands in a slot sealed >=3 barriers earlier; every read confirmed by the
// previous tile boundary's vmcnt(4). Swizzle: 16B chunk (row,ck) at pos ck^(row&7) (uniform
// 8 lanes/bank-quad = b128 minimum, 0 conflicts verified r2/r3), pre-swizzled global source.
__device__ __forceinline__ void stc(float* p, float v) { *p = v; }
__device__ __forceinline__ void stc(__hip_bfloat16* p, float v) { *p = __float2bfloat16(v); }

template <typename TOUT, int NT>
__global__ __launch_bounds__(512, 2) void gemm256p8_kernel(
    const __hip_bfloat16* __restrict__ A, const __hip_bfloat16* __restrict__ Bt,
    TOUT* __restrict__ C, int M, int N, int K) {
  __shared__ __align__(16) char lds[131072];
  const int tid = threadIdx.x;
  const int lane = tid & 63;
  const int wave = tid >> 6;

  // XCD-aware bijective swizzle (grid 4 x 64 = 256 blocks = 8 XCDs x 32)
  int wg = blockIdx.y * gridDim.x + blockIdx.x;
  wg = (wg & 7) * 32 + (wg >> 3);
  const int bx = wg & 3;
  const int by = wg >> 2;
  const long bm = (long)by * 256;
  const long bn = (long)bx * 256;

  // ---- staging sources (pre-swizzled global addr; LDS dest linear) ----
  const int ckl = ((tid & 7) ^ ((tid >> 3) & 7)) * 8;  // logical k-chunk for this thread
  const __hip_bfloat16* sA = A  + (bm + (tid >> 3)) * (long)K + ckl;
  const __hip_bfloat16* sB = Bt + (bn + (tid >> 3)) * (long)K + ckl;
  char* dA = (char*)lds + wave * 1024;           // + slot*16384 (+8192 for L1)
  char* dB = (char*)lds + 65536 + wave * 1024;

  // ---- reader constants ----
  const int wm = wave >> 2, wn = wave & 3;
  const int fr = lane & 15, q = lane >> 4;
  const int pp0 = (q ^ (fr & 7)) << 4;           // swizzled 16B pos, kb=0
  const int pp1 = ((q ^ (fr & 7)) ^ 4) << 4;     // kb=1
  const char* ldsc = (const char*)lds;
  const int rowA = (wm * 64 + fr) * 128;         // A byte row base within slot
  const int rowB = 65536 + (wn * 32 + fr) * 128; // B byte row base within slot

  f32x4 acc[8][4] = {};

#define STG_A(h) do {                                                        \
    const long _o = (long)(((h) & 1) * 128) * K + ((h) >> 1) * 64;           \
    char* _d = dA + ((h) & 3) * 16384;                                       \
    gload_lds16(sA + _o, _d);                                                \
    gload_lds16(sA + _o + 64l * K, _d + 8192); } while (0)
#define STG_B(h) do {                                                        \
    const long _o = (long)(((h) & 1) * 128) * K + ((h) >> 1) * 64;           \
    char* _d = dB + ((h) & 3) * 16384;                                       \
    gload_lds16(sB + _o, _d);                                                \
    gload_lds16(sB + _o + 64l * K, _d + 8192); } while (0)
#define RD_A(av, sl) do { _Pragma("unroll")                                  \
    for (int f = 0; f < 4; ++f) {                                            \
      av[f * 2 + 0] = *(const bf16x8*)(ldsc + (sl) * 16384 + rowA + f * 2048 + pp0); \
      av[f * 2 + 1] = *(const bf16x8*)(ldsc + (sl) * 16384 + rowA + f * 2048 + pp1); } } while (0)
#define RD_B(bv, sl) do { _Pragma("unroll")                                  \
    for (int g = 0; g < 2; ++g) {                                            \
      bv[g * 2 + 0] = *(const bf16x8*)(ldsc + (sl) * 16384 + rowB + g * 2048 + pp0); \
      bv[g * 2 + 1] = *(const bf16x8*)(ldsc + (sl) * 16384 + rowB + g * 2048 + pp1); } } while (0)
#define MFMA_Q(rq, cq, av, bv) do {                                          \
    __builtin_amdgcn_s_setprio(1);                                           \
    _Pragma("unroll")                                                        \
    for (int kb = 0; kb < 2; ++kb)                                           \
      _Pragma("unroll")                                                      \
      for (int f = 0; f < 4; ++f)                                            \
        _Pragma("unroll")                                                    \
        for (int g = 0; g < 2; ++g)                                          \
          acc[(rq) * 4 + f][(cq) * 2 + g] = __builtin_amdgcn_mfma_f32_16x16x32_bf16( \
              av[f * 2 + kb], bv[g * 2 + kb], acc[(rq) * 4 + f][(cq) * 2 + g], 0, 0, 0); \
    __builtin_amdgcn_s_setprio(0); } while (0)
#define SBAR()  asm volatile("s_barrier" ::: "memory")
#define LGKM0() do { asm volatile("s_waitcnt lgkmcnt(0)" ::: "memory");      \
    __builtin_amdgcn_sched_barrier(0); } while (0)

  // prologue: tile0 halves (A0,B0,A1,B1) + tile1 half0 (A2,B2); confirm first 8 loads
  STG_A(0); STG_B(0); STG_A(1); STG_B(1);
  STG_A(2); STG_B(2);
  asm volatile("s_waitcnt vmcnt(4)" ::: "memory");
  SBAR();

#pragma unroll 2
  for (int t = 0; t < NT; ++t) {
    const int s0 = (2 * t) & 3, s1 = (2 * t + 1) & 3;
    bf16x8 av[8], bv0[4], bv1[4];
    // ---- phase 1: Q(0,0) — 12 reads, stage both halves h=2t+3 ----
    RD_A(av, s0); RD_B(bv0, s0);
    if (t < NT - 1) { STG_A(2 * t + 3); STG_B(2 * t + 3); }
    asm volatile("s_waitcnt lgkmcnt(8)" ::: "memory");
    SBAR();
    LGKM0();
    MFMA_Q(0, 0, av, bv0);
    SBAR();
    // ---- phase 2: Q(0,1) — 4 reads (reuse av) ----
    RD_B(bv1, s1);
    SBAR();
    LGKM0();
    MFMA_Q(0, 1, av, bv1);
    SBAR();
    // ---- phase 3: Q(1,0) — 8 reads (reuse bv0), stage A(2t+4) ----
    RD_A(av, s1);
    if (t < NT - 2) STG_A(2 * t + 4);
    SBAR();
    LGKM0();
    MFMA_Q(1, 0, av, bv0);
    SBAR();
    // ---- phase 4: Q(1,1) — 0 reads (reuse av,bv1), stage B(2t+4), boundary vmcnt ----
    if (t < NT - 2) STG_B(2 * t + 4);
    SBAR();
    MFMA_Q(1, 1, av, bv1);
    asm volatile("s_waitcnt vmcnt(4)" ::: "memory");
    SBAR();
  }
#undef STG_A
#undef STG_B
#undef RD_A
#undef RD_B
#undef MFMA_Q
#undef SBAR
#undef LGKM0

  // epilogue: C/D layout (m89-verified): col = lane&15, row = (lane>>4)*4 + reg
#pragma unroll
  for (int rq = 0; rq < 2; ++rq)
#pragma unroll
    for (int f = 0; f < 4; ++f)
#pragma unroll
      for (int cq = 0; cq < 2; ++cq)
#pragma unroll
        for (int g = 0; g < 2; ++g)
#pragma unroll
          for (int r = 0; r < 4; ++r) {
            const long row = bm + rq * 128 + wm * 64 + f * 16 + q * 4 + r;
            const long col = bn + cq * 128 + wn * 32 + g * 16 + fr;
            stc(&C[row * (long)N + col], acc[rq * 4 + f][cq * 2 + g][r]);
          }
}

// ---------------- scan phase 1: chunk-local finals only ----------------
__global__ __launch_bounds__(256) void scan_finals_kernel(
    const __hip_bfloat16* __restrict__ xi, float* __restrict__ finals,
    const float* __restrict__ alpha) {
  const int e0 = threadIdx.x * 4;
  const int c = blockIdx.y;
  const int b = blockIdx.z;
  const float a = sigm(alpha[e0 >> 6]);
  const float om = 1.f - a;
  long base = ((long)b * N_ + (long)c * CL_) * INNER_ + e0;
  float y0 = 0.f, y1 = 0.f, y2 = 0.f, y3 = 0.f;
  for (int t = 0; t < CL_; ++t) {
    ushort4 u = *(const ushort4*)(xi + base);
    y0 = om * y0 + a * bf2f(u.x);
    y1 = om * y1 + a * bf2f(u.y);
    y2 = om * y2 + a * bf2f(u.z);
    y3 = om * y3 + a * bf2f(u.w);
    base += INNER_;
  }
  float4 f4 = make_float4(y0, y1, y2, y3);
  *reinterpret_cast<float4*>(&finals[((long)b * CH_ + c) * INNER_ + e0]) = f4;
}

// ---------------- scan phase 2: carry sweep over chunks ----------------
__global__ __launch_bounds__(256) void scan_carry_kernel(
    const float* __restrict__ finals, float* __restrict__ carries,
    const float* __restrict__ alpha) {
  const int g = blockIdx.x * 256 + threadIdx.x;  // 0..B_*INNER_-1
  const int b = g >> 10;
  const int e = g & 1023;
  const float a = sigm(alpha[e >> 6]);
  const float dc = powf(1.f - a, (float)CL_);
  float carry = 0.f;
  for (int c = 0; c < CH_; ++c) {
    const long idx = ((long)b * CH_ + c) * INNER_ + e;
    carries[idx] = carry;
    carry = finals[idx] + dc * carry;
  }
}

// ---------------- scan phase 3: full EMA seeded by carry ----------------
__global__ __launch_bounds__(256) void scan_apply_kernel(
    const __hip_bfloat16* __restrict__ xi, __hip_bfloat16* __restrict__ y,
    const float* __restrict__ carries, const float* __restrict__ alpha) {
  const int e0 = threadIdx.x * 4;
  const int c = blockIdx.y;
  const int b = blockIdx.z;
  const float a = sigm(alpha[e0 >> 6]);
  const float om = 1.f - a;
  const float4 cr = *reinterpret_cast<const float4*>(
      &carries[((long)b * CH_ + c) * INNER_ + e0]);
  float y0 = cr.x, y1 = cr.y, y2 = cr.z, y3 = cr.w;
  long base = ((long)b * N_ + (long)c * CL_) * INNER_ + e0;
  for (int t = 0; t < CL_; ++t) {
    ushort4 u = *(const ushort4*)(xi + base);
    y0 = om * y0 + a * bf2f(u.x);
    y1 = om * y1 + a * bf2f(u.y);
    y2 = om * y2 + a * bf2f(u.z);
    y3 = om * y3 + a * bf2f(u.w);
    ushort4 o;
    o.x = f2bf(y0); o.y = f2bf(y1); o.z = f2bf(y2); o.w = f2bf(y3);
    *(ushort4*)(y + base) = o;
    base += INNER_;
  }
}

extern "C" void kernel_launch(void* const* d_in, const int* in_sizes, int n_in,
                              void* d_out, int out_size, void* d_ws, size_t ws_size,
                              hipStream_t stream) {
  const float* x     = (const float*)d_in[0];
  const float* gamma = (const float*)d_in[1];
  const float* beta  = (const float*)d_in[2];
  const float* alpha = (const float*)d_in[3];
  const float* w_in  = (const float*)d_in[4];
  const float* w_out = (const float*)d_in[5];
  float* out = (float*)d_out;
  char* ws = (char*)d_ws;

  // ws layout (40 MB total):
  __hip_bfloat16* xn = (__hip_bfloat16*)ws;                       // 32 MB (reused as y)
  __hip_bfloat16* wi = (__hip_bfloat16*)(ws + (32l << 20));       // 2 MB
  __hip_bfloat16* wo = (__hip_bfloat16*)(ws + (34l << 20));       // 2 MB
  float* finals      = (float*)(ws + (36l << 20));                // 2 MB
  float* carries     = (float*)(ws + (38l << 20));                // 2 MB
  // xi (bf16, 32 MB) lives in d_out's first half; consumed before GEMM2 writes d_out
  __hip_bfloat16* xi = (__hip_bfloat16*)d_out;

  cast2_kernel<<<2048, 256, 0, stream>>>(w_in, w_out, wi, wo);

  ln_kernel<<<M_, 256, 0, stream>>>(x, gamma, beta, xn);

  // xi[m,e] = sum_d xn[m,d] * w_in[e,d]   (grid 4 x 64 = 256 blocks)
  gemm256p8_kernel<__hip_bfloat16, 16>
      <<<dim3(INNER_ / 256, M_ / 256), 512, 0, stream>>>(xn, wi, xi, M_, INNER_, D_);

  __hip_bfloat16* y = xn;  // overwrite xn (consumed by GEMM1)
  scan_finals_kernel<<<dim3(1, CH_, B_), 256, 0, stream>>>(xi, finals, alpha);
  scan_carry_kernel<<<(B_ * INNER_) / 256, 256, 0, stream>>>(finals, carries, alpha);
  scan_apply_kernel<<<dim3(1, CH_, B_), 256, 0, stream>>>(xi, y, carries, alpha);

  // out[m,d] = sum_e y[m,e] * w_out[d,e]
  gemm256p8_kernel<float, 16>
      <<<dim3(D_ / 256, M_ / 256), 512, 0, stream>>>(y, wo, out, M_, D_, INNER_);
}